// Round 1
// baseline (9683.740 us; speedup 1.0000x reference)
//
#include <hip/hip_runtime.h>
#include <hip/hip_bf16.h>

#define EMBED   1024
#define HIDDEN  2048
#define G4      8192   // 4*HIDDEN
#define LENGTH  4096

typedef unsigned int   u32;
typedef unsigned short u16;
typedef __attribute__((ext_vector_type(4))) float f32x4;
typedef __attribute__((ext_vector_type(8))) short short8;

__device__ __forceinline__ u16 f2bf(float x){
  __hip_bfloat16 h = __float2bfloat16(x);   // RNE
  return __builtin_bit_cast(u16, h);
}
__device__ __forceinline__ float bf2f(u16 b){
  return __uint_as_float(((u32)b) << 16);
}

#if __has_builtin(__builtin_amdgcn_fdot2_f32_bf16)
typedef __attribute__((ext_vector_type(2))) __bf16 bf16x2;
__device__ __forceinline__ float dot2acc(u32 a, u32 b, float c){
  return __builtin_amdgcn_fdot2_f32_bf16(__builtin_bit_cast(bf16x2, a),
                                         __builtin_bit_cast(bf16x2, b), c, false);
}
#else
__device__ __forceinline__ float dot2acc(u32 a, u32 b, float c){
  float r = c;
  r += __uint_as_float(a << 16)          * __uint_as_float(b << 16);
  r += __uint_as_float(a & 0xffff0000u)  * __uint_as_float(b & 0xffff0000u);
  return r;
}
#endif

__device__ __forceinline__ float fsig(float x){ return 1.f/(1.f + __expf(-x)); }
__device__ __forceinline__ float ftanh_(float x){ return 1.f - 2.f/(1.f + __expf(2.f*x)); }

// ---------------- fp32 -> bf16 conversion (vectorized) ----------------
__global__ void conv_bf16(const float* __restrict__ src, u16* __restrict__ dst, int n4){
  int i = blockIdx.x * blockDim.x + threadIdx.x;
  if (i < n4){
    float4 v = reinterpret_cast<const float4*>(src)[i];
    ushort4 o;
    o.x = f2bf(v.x); o.y = f2bf(v.y); o.z = f2bf(v.z); o.w = f2bf(v.w);
    reinterpret_cast<ushort4*>(dst)[i] = o;
  }
}

// ---------------- x_proj GEMM: C[m][n] = sum_k A[m][k]*B[n][k] + bias(n) ----------------
// A = x_bf16 [4096][1024], B = Wih_bf16 [8192][1024] (B^T form), C = xp bf16 [4096][8192]
__global__ __launch_bounds__(256) void gemm_xproj(
    const u16* __restrict__ A, const u16* __restrict__ B,
    const float* __restrict__ b_ih, const float* __restrict__ b_hh,
    u16* __restrict__ C)
{
  __shared__ __align__(16) u16 As[64][40];  // 64 rows x 32 k, padded to 40
  __shared__ __align__(16) u16 Bs[64][40];
  const int tid  = threadIdx.x;
  const int lane = tid & 63, wid = tid >> 6;
  const int wr = wid >> 1, wc = wid & 1;          // 2x2 wave grid, 32x32 per wave
  const int m0 = blockIdx.y * 64, n0 = blockIdx.x * 64;
  const int srow = tid >> 2, sseg = (tid & 3) * 8;

  f32x4 acc[2][2] = {};
  for (int k0 = 0; k0 < EMBED; k0 += 32){
    *(short8*)&As[srow][sseg] = *(const short8*)&A[(size_t)(m0 + srow) * EMBED + k0 + sseg];
    *(short8*)&Bs[srow][sseg] = *(const short8*)&B[(size_t)(n0 + srow) * EMBED + k0 + sseg];
    __syncthreads();
    const int rr = lane & 15, kg = (lane >> 4) * 8;
    #pragma unroll
    for (int mi = 0; mi < 2; ++mi){
      short8 a = *(const short8*)&As[wr*32 + mi*16 + rr][kg];
      #pragma unroll
      for (int ni = 0; ni < 2; ++ni){
        short8 b = *(const short8*)&Bs[wc*32 + ni*16 + rr][kg];
        acc[mi][ni] = __builtin_amdgcn_mfma_f32_16x16x32_bf16(a, b, acc[mi][ni], 0, 0, 0);
      }
    }
    __syncthreads();
  }
  // epilogue: D[row=(lane>>4)*4+r][col=lane&15] (verified C/D mapping)
  const int rr = lane & 15, rg = (lane >> 4) * 4;
  #pragma unroll
  for (int ni = 0; ni < 2; ++ni){
    int n = n0 + wc*32 + ni*16 + rr;
    float bias = b_ih[n] + b_hh[n];
    #pragma unroll
    for (int mi = 0; mi < 2; ++mi){
      #pragma unroll
      for (int r = 0; r < 4; ++r){
        int m = m0 + wr*32 + mi*16 + rg + r;
        C[(size_t)m * G4 + n] = f2bf(acc[mi][ni][r] + bias);
      }
    }
  }
}

// ---------------- persistent LSTM scan ----------------
// 256 WGs (1/CU) x 512 threads (8 waves). Wave w of WG wg owns hidden index
// j = wg*8 + w: gate rows {g*2048 + j}, g=0..3 (i,f,g,o). Entire W_hh slice is
// register-resident as packed bf16 pairs: lane holds cols [lane*32, lane*32+32)
// of its wave's 4 rows = 64 VGPRs. h broadcast: h_tagged[2][2048] words of
// (tag<<16 | bf16(h)) with agent-scope atomics; double-buffered by step parity.
__global__ __launch_bounds__(512) void lstm_scan(
    const float* __restrict__ Whh,   // [8192][2048] fp32
    const u16*  __restrict__ xp,     // [4096][8192] bf16
    u32* htag)                       // [2][2048]
{
  const int wg = blockIdx.x;
  const int tid = threadIdx.x;
  const int w = tid >> 6, lane = tid & 63;
  __shared__ __align__(16) u16 h_bf[HIDDEN];

  // stage weights into registers (one-time, ~256KB/CU from HBM)
  u32 wreg[4][16];
  #pragma unroll
  for (int g = 0; g < 4; ++g){
    const float* src = Whh + (size_t)(g*HIDDEN + wg*8 + w) * HIDDEN + lane*32;
    #pragma unroll
    for (int p = 0; p < 8; ++p){
      float4 v = *(const float4*)(src + p*4);
      wreg[g][2*p]   = (u32)f2bf(v.x) | ((u32)f2bf(v.y) << 16);
      wreg[g][2*p+1] = (u32)f2bf(v.z) | ((u32)f2bf(v.w) << 16);
    }
  }
  float c_reg = 0.f;
  const int pb = tid * 4;   // this thread's 4 h-words

  for (int t = 0; t < LENGTH; ++t){
    // prefetch this wave's 4 x_proj entries (independent of h -> hides latency)
    float xr0 = 0.f, xr1 = 0.f, xr2 = 0.f, xr3 = 0.f;
    if (lane == 0){
      const u16* xrow = xp + (size_t)t * G4 + wg*8 + w;
      xr0 = bf2f(xrow[0]);
      xr1 = bf2f(xrow[HIDDEN]);
      xr2 = bf2f(xrow[2*HIDDEN]);
      xr3 = bf2f(xrow[3*HIDDEN]);
    }
    // acquire step-t h (tag == t), buffer t&1
    u32* src = htag + ((t & 1) << 11);
    const u32 want = (u32)t;
    u32 v0, v1, v2, v3;
    for (;;){
      v0 = __hip_atomic_load(&src[pb+0], __ATOMIC_RELAXED, __HIP_MEMORY_SCOPE_AGENT);
      v1 = __hip_atomic_load(&src[pb+1], __ATOMIC_RELAXED, __HIP_MEMORY_SCOPE_AGENT);
      v2 = __hip_atomic_load(&src[pb+2], __ATOMIC_RELAXED, __HIP_MEMORY_SCOPE_AGENT);
      v3 = __hip_atomic_load(&src[pb+3], __ATOMIC_RELAXED, __HIP_MEMORY_SCOPE_AGENT);
      if ((v0 >> 16) == want && (v1 >> 16) == want &&
          (v2 >> 16) == want && (v3 >> 16) == want) break;
      __builtin_amdgcn_s_sleep(1);
    }
    ushort4 hv;
    hv.x = (u16)v0; hv.y = (u16)v1; hv.z = (u16)v2; hv.w = (u16)v3;
    *(ushort4*)&h_bf[pb] = hv;
    __syncthreads();

    // 4 row-dots from register-resident weights
    const uint4* hp4 = (const uint4*)&h_bf[lane * 32];
    uint4 h0 = hp4[0], h1 = hp4[1], h2 = hp4[2], h3 = hp4[3];
    u32 hp[16] = { h0.x, h0.y, h0.z, h0.w,  h1.x, h1.y, h1.z, h1.w,
                   h2.x, h2.y, h2.z, h2.w,  h3.x, h3.y, h3.z, h3.w };
    float a0 = 0.f, a1 = 0.f, a2 = 0.f, a3 = 0.f;
    #pragma unroll
    for (int p = 0; p < 16; ++p){
      a0 = dot2acc(wreg[0][p], hp[p], a0);
      a1 = dot2acc(wreg[1][p], hp[p], a1);
      a2 = dot2acc(wreg[2][p], hp[p], a2);
      a3 = dot2acc(wreg[3][p], hp[p], a3);
    }
    #pragma unroll
    for (int m = 32; m >= 1; m >>= 1){
      a0 += __shfl_xor(a0, m, 64);
      a1 += __shfl_xor(a1, m, 64);
      a2 += __shfl_xor(a2, m, 64);
      a3 += __shfl_xor(a3, m, 64);
    }
    if (lane == 0){
      float gi = fsig (a0 + xr0);
      float gf = fsig (a1 + xr1);
      float gg = ftanh_(a2 + xr2);
      float go = fsig (a3 + xr3);
      c_reg = gf * c_reg + gi * gg;
      float h = go * ftanh_(c_reg);
      u32 word = ((u32)(t + 1) << 16) | (u32)f2bf(h);
      __hip_atomic_store(&htag[(((t + 1) & 1) << 11) + wg*8 + w], word,
                         __ATOMIC_RELAXED, __HIP_MEMORY_SCOPE_AGENT);
    }
    __syncthreads();  // protect h_bf from next-step overwrite
  }
}

// ---------------- final head: sigmoid(h . W_fc + b_fc) ----------------
__global__ __launch_bounds__(256) void head_k(const u32* __restrict__ htag,
                                              const float* __restrict__ Wfc,
                                              const float* __restrict__ bfc,
                                              float* __restrict__ out){
  __shared__ float red[256];
  int tid = threadIdx.x;
  float s = 0.f;
  #pragma unroll
  for (int k = 0; k < 8; ++k){
    int j = tid * 8 + k;
    s += bf2f((u16)(htag[j] & 0xffffu)) * Wfc[j];   // tag 4096 lives in buffer 0
  }
  red[tid] = s;
  __syncthreads();
  for (int k = 128; k > 0; k >>= 1){
    if (tid < k) red[tid] += red[tid + k];
    __syncthreads();
  }
  if (tid == 0) out[0] = 1.f / (1.f + __expf(-(red[0] + bfc[0])));
}

// ---------------- launch ----------------
extern "C" void kernel_launch(void* const* d_in, const int* in_sizes, int n_in,
                              void* d_out, int out_size, void* d_ws, size_t ws_size,
                              hipStream_t stream){
  const float* x   = (const float*)d_in[0];   // [1,4096,1024]
  const float* Wih = (const float*)d_in[1];   // [8192,1024]
  const float* Whh = (const float*)d_in[2];   // [8192,2048]
  const float* bih = (const float*)d_in[3];   // [8192]
  const float* bhh = (const float*)d_in[4];   // [8192]
  const float* Wfc = (const float*)d_in[5];   // [1,2048]
  const float* bfc = (const float*)d_in[6];   // [1]
  float* out = (float*)d_out;

  // workspace layout (needs ~92.3 MB)
  char* ws = (char*)d_ws;
  u16* xp     = (u16*)(ws);                    // 4096*8192*2 = 67108864
  u16* x_bf   = (u16*)(ws + 67108864);         // 8388608
  u16* wih_bf = (u16*)(ws + 75497472);         // 16777216
  u32* htag   = (u32*)(ws + 92274688);         // 2*2048*4 = 16384

  hipMemsetAsync(htag, 0, 2 * HIDDEN * sizeof(u32), stream);
  conv_bf16<<<(EMBED*LENGTH/4 + 255)/256, 256, 0, stream>>>(x, x_bf, EMBED*LENGTH/4);
  conv_bf16<<<(G4*EMBED/4 + 255)/256, 256, 0, stream>>>(Wih, wih_bf, G4*EMBED/4);
  dim3 gg(G4/64, LENGTH/64);
  gemm_xproj<<<gg, 256, 0, stream>>>(x_bf, wih_bf, bih, bhh, xp);
  lstm_scan<<<256, 512, 0, stream>>>(Whh, xp, htag);
  head_k<<<1, 256, 0, stream>>>(htag, Wfc, bfc, out);
}

// Round 2
// 9085.208 us; speedup vs baseline: 1.0659x; 1.0659x over previous
//
#include <hip/hip_runtime.h>
#include <hip/hip_bf16.h>

#define EMBED   1024
#define HIDDEN  2048
#define G4      8192   // 4*HIDDEN
#define LENGTH  4096

typedef unsigned int   u32;
typedef unsigned short u16;
typedef __attribute__((ext_vector_type(4))) float f32x4;
typedef __attribute__((ext_vector_type(8))) short short8;

__device__ __forceinline__ u16 f2bf(float x){
  __hip_bfloat16 h = __float2bfloat16(x);   // RNE
  return __builtin_bit_cast(u16, h);
}
__device__ __forceinline__ float bf2f(u16 b){
  return __uint_as_float(((u32)b) << 16);
}

#if __has_builtin(__builtin_amdgcn_fdot2_f32_bf16)
typedef __attribute__((ext_vector_type(2))) __bf16 bf16x2;
__device__ __forceinline__ float dot2acc(u32 a, u32 b, float c){
  return __builtin_amdgcn_fdot2_f32_bf16(__builtin_bit_cast(bf16x2, a),
                                         __builtin_bit_cast(bf16x2, b), c, false);
}
#else
__device__ __forceinline__ float dot2acc(u32 a, u32 b, float c){
  float r = c;
  r += __uint_as_float(a << 16)          * __uint_as_float(b << 16);
  r += __uint_as_float(a & 0xffff0000u)  * __uint_as_float(b & 0xffff0000u);
  return r;
}
#endif

__device__ __forceinline__ float fsig(float x){ return 1.f/(1.f + __expf(-x)); }
__device__ __forceinline__ float ftanh_(float x){ return 1.f - 2.f/(1.f + __expf(2.f*x)); }

// ---------------- fp32 -> bf16 conversion (vectorized) ----------------
__global__ void conv_bf16(const float* __restrict__ src, u16* __restrict__ dst, int n4){
  int i = blockIdx.x * blockDim.x + threadIdx.x;
  if (i < n4){
    float4 v = reinterpret_cast<const float4*>(src)[i];
    ushort4 o;
    o.x = f2bf(v.x); o.y = f2bf(v.y); o.z = f2bf(v.z); o.w = f2bf(v.w);
    reinterpret_cast<ushort4*>(dst)[i] = o;
  }
}

// ---------------- x_proj GEMM: C[m][n] = sum_k A[m][k]*B[n][k] + bias(n) ----------------
__global__ __launch_bounds__(256) void gemm_xproj(
    const u16* __restrict__ A, const u16* __restrict__ B,
    const float* __restrict__ b_ih, const float* __restrict__ b_hh,
    u16* __restrict__ C)
{
  __shared__ __align__(16) u16 As[64][40];  // 64 rows x 32 k, padded to 40
  __shared__ __align__(16) u16 Bs[64][40];
  const int tid  = threadIdx.x;
  const int lane = tid & 63, wid = tid >> 6;
  const int wr = wid >> 1, wc = wid & 1;          // 2x2 wave grid, 32x32 per wave
  const int m0 = blockIdx.y * 64, n0 = blockIdx.x * 64;
  const int srow = tid >> 2, sseg = (tid & 3) * 8;

  f32x4 acc[2][2] = {};
  for (int k0 = 0; k0 < EMBED; k0 += 32){
    *(short8*)&As[srow][sseg] = *(const short8*)&A[(size_t)(m0 + srow) * EMBED + k0 + sseg];
    *(short8*)&Bs[srow][sseg] = *(const short8*)&B[(size_t)(n0 + srow) * EMBED + k0 + sseg];
    __syncthreads();
    const int rr = lane & 15, kg = (lane >> 4) * 8;
    #pragma unroll
    for (int mi = 0; mi < 2; ++mi){
      short8 a = *(const short8*)&As[wr*32 + mi*16 + rr][kg];
      #pragma unroll
      for (int ni = 0; ni < 2; ++ni){
        short8 b = *(const short8*)&Bs[wc*32 + ni*16 + rr][kg];
        acc[mi][ni] = __builtin_amdgcn_mfma_f32_16x16x32_bf16(a, b, acc[mi][ni], 0, 0, 0);
      }
    }
    __syncthreads();
  }
  const int rr = lane & 15, rg = (lane >> 4) * 4;
  #pragma unroll
  for (int ni = 0; ni < 2; ++ni){
    int n = n0 + wc*32 + ni*16 + rr;
    float bias = b_ih[n] + b_hh[n];
    #pragma unroll
    for (int mi = 0; mi < 2; ++mi){
      #pragma unroll
      for (int r = 0; r < 4; ++r){
        int m = m0 + wr*32 + mi*16 + rg + r;
        C[(size_t)m * G4 + n] = f2bf(acc[mi][ni][r] + bias);
      }
    }
  }
}

// ---------------- persistent LSTM scan ----------------
// 256 WGs (1/CU) x 512 threads (8 waves). Wave w of WG wg owns hidden unit
// j = wg*8 + w: gate rows {g*2048 + j}, g=0..3. W_hh register-resident:
// __launch_bounds__(512,2) (2 waves/EU) allows ~256 VGPRs -> no spill.
// Column->lane mapping chosen so every LDS access is conflict-free:
//   lane l, read r (0..3) covers columns c = r*512 + l*8 + {0..7}
//   (ds_read_b128 at byte r*1024 + l*16: lane-contiguous, 2-way free).
// h broadcast: htag[2][2048] words (tag<<16 | bf16(h)), agent-scope atomics,
// double-buffered by step parity. Thread tid polls words {tid + k*512} so each
// poll load is a wave-contiguous coalesced 256B line.
__global__ __launch_bounds__(512, 2) void lstm_scan(
    const float* __restrict__ Whh,   // [8192][2048] fp32
    const u16*  __restrict__ xp,     // [4096][8192] bf16
    u32* htag)                       // [2][2048]
{
  const int wg = blockIdx.x;
  const int tid = threadIdx.x;
  const int w = tid >> 6, lane = tid & 63;
  __shared__ __align__(16) u16 h_bf[4][512];

  // stage weights into registers, permuted to match the LDS read mapping:
  // wreg[g][r*4+q] = columns (r*512 + lane*8 + 2q, +1) of row g*2048+wg*8+w
  u32 wreg[4][16];
  #pragma unroll
  for (int g = 0; g < 4; ++g){
    const float* row = Whh + (size_t)(g*HIDDEN + wg*8 + w) * HIDDEN;
    #pragma unroll
    for (int r = 0; r < 4; ++r){
      const float* src = row + r*512 + lane*8;
      float4 v0 = *(const float4*)(src);
      float4 v1 = *(const float4*)(src + 4);
      wreg[g][r*4+0] = (u32)f2bf(v0.x) | ((u32)f2bf(v0.y) << 16);
      wreg[g][r*4+1] = (u32)f2bf(v0.z) | ((u32)f2bf(v0.w) << 16);
      wreg[g][r*4+2] = (u32)f2bf(v1.x) | ((u32)f2bf(v1.y) << 16);
      wreg[g][r*4+3] = (u32)f2bf(v1.z) | ((u32)f2bf(v1.w) << 16);
    }
  }
  float c_reg = 0.f;

  for (int t = 0; t < LENGTH; ++t){
    // prefetch this wave's 4 x_proj entries (independent of h)
    float xr0 = 0.f, xr1 = 0.f, xr2 = 0.f, xr3 = 0.f;
    if (lane == 0){
      const u16* xrow = xp + (size_t)t * G4 + wg*8 + w;
      xr0 = bf2f(xrow[0]);
      xr1 = bf2f(xrow[HIDDEN]);
      xr2 = bf2f(xrow[2*HIDDEN]);
      xr3 = bf2f(xrow[3*HIDDEN]);
    }
    // acquire step-t h (tag == t), buffer t&1; coalesced poll
    u32* src = htag + ((t & 1) << 11);
    const u32 want = (u32)t;
    u32 v0, v1, v2, v3;
    for (;;){
      v0 = __hip_atomic_load(&src[tid       ], __ATOMIC_RELAXED, __HIP_MEMORY_SCOPE_AGENT);
      v1 = __hip_atomic_load(&src[tid +  512], __ATOMIC_RELAXED, __HIP_MEMORY_SCOPE_AGENT);
      v2 = __hip_atomic_load(&src[tid + 1024], __ATOMIC_RELAXED, __HIP_MEMORY_SCOPE_AGENT);
      v3 = __hip_atomic_load(&src[tid + 1536], __ATOMIC_RELAXED, __HIP_MEMORY_SCOPE_AGENT);
      if ((v0 >> 16) == want && (v1 >> 16) == want &&
          (v2 >> 16) == want && (v3 >> 16) == want) break;
      __builtin_amdgcn_s_sleep(1);
    }
    h_bf[0][tid] = (u16)v0;
    h_bf[1][tid] = (u16)v1;
    h_bf[2][tid] = (u16)v2;
    h_bf[3][tid] = (u16)v3;
    __syncthreads();

    // 4 conflict-free ds_read_b128: h words for columns r*512 + lane*8 + i
    uint4 h0 = *(const uint4*)&h_bf[0][lane*8];
    uint4 h1 = *(const uint4*)&h_bf[1][lane*8];
    uint4 h2 = *(const uint4*)&h_bf[2][lane*8];
    uint4 h3 = *(const uint4*)&h_bf[3][lane*8];
    u32 hp[16] = { h0.x, h0.y, h0.z, h0.w,  h1.x, h1.y, h1.z, h1.w,
                   h2.x, h2.y, h2.z, h2.w,  h3.x, h3.y, h3.z, h3.w };
    float a0 = 0.f, a1 = 0.f, a2 = 0.f, a3 = 0.f;
    #pragma unroll
    for (int p = 0; p < 16; ++p){
      a0 = dot2acc(wreg[0][p], hp[p], a0);
      a1 = dot2acc(wreg[1][p], hp[p], a1);
      a2 = dot2acc(wreg[2][p], hp[p], a2);
      a3 = dot2acc(wreg[3][p], hp[p], a3);
    }
    #pragma unroll
    for (int m = 32; m >= 1; m >>= 1){
      a0 += __shfl_xor(a0, m, 64);
      a1 += __shfl_xor(a1, m, 64);
      a2 += __shfl_xor(a2, m, 64);
      a3 += __shfl_xor(a3, m, 64);
    }
    if (lane == 0){
      float gi = fsig (a0 + xr0);
      float gf = fsig (a1 + xr1);
      float gg = ftanh_(a2 + xr2);
      float go = fsig (a3 + xr3);
      c_reg = gf * c_reg + gi * gg;
      float h = go * ftanh_(c_reg);
      u32 word = ((u32)(t + 1) << 16) | (u32)f2bf(h);
      __hip_atomic_store(&htag[(((t + 1) & 1) << 11) + wg*8 + w], word,
                         __ATOMIC_RELAXED, __HIP_MEMORY_SCOPE_AGENT);
    }
    // single barrier per step: all waves of the WG advance in lock-step, so
    // next step's h_bf writes (same buffer) can't race this step's reads.
  }
}

// ---------------- final head: sigmoid(h . W_fc + b_fc) ----------------
__global__ __launch_bounds__(256) void head_k(const u32* __restrict__ htag,
                                              const float* __restrict__ Wfc,
                                              const float* __restrict__ bfc,
                                              float* __restrict__ out){
  __shared__ float red[256];
  int tid = threadIdx.x;
  float s = 0.f;
  #pragma unroll
  for (int k = 0; k < 8; ++k){
    int j = tid * 8 + k;
    s += bf2f((u16)(htag[j] & 0xffffu)) * Wfc[j];   // tag 4096 lives in buffer 0
  }
  red[tid] = s;
  __syncthreads();
  for (int k = 128; k > 0; k >>= 1){
    if (tid < k) red[tid] += red[tid + k];
    __syncthreads();
  }
  if (tid == 0) out[0] = 1.f / (1.f + __expf(-(red[0] + bfc[0])));
}

// ---------------- launch ----------------
extern "C" void kernel_launch(void* const* d_in, const int* in_sizes, int n_in,
                              void* d_out, int out_size, void* d_ws, size_t ws_size,
                              hipStream_t stream){
  const float* x   = (const float*)d_in[0];   // [1,4096,1024]
  const float* Wih = (const float*)d_in[1];   // [8192,1024]
  const float* Whh = (const float*)d_in[2];   // [8192,2048]
  const float* bih = (const float*)d_in[3];   // [8192]
  const float* bhh = (const float*)d_in[4];   // [8192]
  const float* Wfc = (const float*)d_in[5];   // [1,2048]
  const float* bfc = (const float*)d_in[6];   // [1]
  float* out = (float*)d_out;

  char* ws = (char*)d_ws;
  u16* xp     = (u16*)(ws);                    // 4096*8192*2 = 67108864
  u16* x_bf   = (u16*)(ws + 67108864);         // 8388608
  u16* wih_bf = (u16*)(ws + 75497472);         // 16777216
  u32* htag   = (u32*)(ws + 92274688);         // 2*2048*4 = 16384

  hipMemsetAsync(htag, 0, 2 * HIDDEN * sizeof(u32), stream);
  conv_bf16<<<(EMBED*LENGTH/4 + 255)/256, 256, 0, stream>>>(x, x_bf, EMBED*LENGTH/4);
  conv_bf16<<<(G4*EMBED/4 + 255)/256, 256, 0, stream>>>(Wih, wih_bf, G4*EMBED/4);
  dim3 gg(G4/64, LENGTH/64);
  gemm_xproj<<<gg, 256, 0, stream>>>(x_bf, wih_bf, bih, bhh, xp);
  lstm_scan<<<256, 512, 0, stream>>>(Whh, xp, htag);
  head_k<<<1, 256, 0, stream>>>(htag, Wfc, bfc, out);
}